// Round 2
// baseline (131.937 us; speedup 1.0000x reference)
//
#include <hip/hip_runtime.h>
#include <math.h>

#define ECE_N_BINS 10
#define ECE_C 128

typedef float f32x4 __attribute__((ext_vector_type(4)));

// ws layout (floats): [0..9] counts, [10..19] conf_sum, [20..29] acc_sum

__global__ __launch_bounds__(256) void ece_main_kernel(
    const float* __restrict__ logits,
    const int*   __restrict__ labels,
    float*       __restrict__ ws,
    int n_rows)
{
    __shared__ float s_bins[3 * ECE_N_BINS];
    const int tid = threadIdx.x;
    if (tid < 3 * ECE_N_BINS) s_bins[tid] = 0.0f;
    __syncthreads();

    const int lane32         = tid & 31;   // 32 lanes cooperate on one row
    const int grp            = tid >> 5;   // 8 row-groups per block
    const int rows_per_block = 256 >> 5;   // 8

    for (int row = blockIdx.x * rows_per_block + grp;
         row < n_rows;
         row += gridDim.x * rows_per_block)
    {
        // One float4 per lane: a full wave instruction covers 2 rows = 1 KB,
        // perfectly contiguous. nt hint: streaming, don't bother caching.
        const f32x4* rp = (const f32x4*)(logits + (long long)row * ECE_C);
        f32x4 a = __builtin_nontemporal_load(rp + lane32);

        // in-lane max/argmax over 4 contiguous values (first occurrence wins)
        const int base = lane32 * 4;
        float v = a[0]; int idx = base;
        if (a[1] > v) { v = a[1]; idx = base + 1; }
        if (a[2] > v) { v = a[2]; idx = base + 2; }
        if (a[3] > v) { v = a[3]; idx = base + 3; }

        // butterfly across the 32-lane group (xor masks < 32 stay in-half)
        #pragma unroll
        for (int m = 1; m < 32; m <<= 1) {
            float ov  = __shfl_xor(v,   m);
            int   oid = __shfl_xor(idx, m);
            if (ov > v || (ov == v && oid < idx)) { v = ov; idx = oid; }
        }

        if (lane32 == 0 && v > 0.0f) {   // valid = conf > 0
            int bin = (int)ceilf(v * (float)ECE_N_BINS) - 1;
            bin = max(0, min(ECE_N_BINS - 1, bin));
            float acc = (idx == labels[row]) ? 1.0f : 0.0f;
            atomicAdd(&s_bins[bin],                  1.0f);
            atomicAdd(&s_bins[ECE_N_BINS + bin],     v);
            atomicAdd(&s_bins[2 * ECE_N_BINS + bin], acc);
        }
    }

    __syncthreads();
    if (tid < 3 * ECE_N_BINS) {
        float val = s_bins[tid];
        if (val != 0.0f) atomicAdd(&ws[tid], val);
    }
}

__global__ void ece_final_kernel(const float* __restrict__ ws,
                                 float* __restrict__ out,
                                 float inv_n)
{
    if (threadIdx.x == 0) {
        float ece = 0.0f;
        #pragma unroll
        for (int b = 0; b < ECE_N_BINS; ++b) {
            float cnt = ws[b];
            if (cnt > 0.0f) {
                float avg_conf = ws[ECE_N_BINS + b]     / cnt;
                float avg_acc  = ws[2 * ECE_N_BINS + b] / cnt;
                ece += fabsf(avg_conf - avg_acc) * cnt * inv_n;
            }
        }
        out[0] = ece;
    }
}

extern "C" void kernel_launch(void* const* d_in, const int* in_sizes, int n_in,
                              void* d_out, int out_size, void* d_ws, size_t ws_size,
                              hipStream_t stream)
{
    const float* logits = (const float*)d_in[0];
    const int*   labels = (const int*)d_in[1];
    float* out = (float*)d_out;
    float* ws  = (float*)d_ws;

    const int n_rows = in_sizes[1];            // labels count = N

    hipMemsetAsync(ws, 0, 3 * ECE_N_BINS * sizeof(float), stream);

    const int block = 256;
    const int rows_per_block = block / 32;     // 8
    int grid = (n_rows + rows_per_block - 1) / rows_per_block;
    if (grid > 2048) grid = 2048;              // grid-stride the rest; 8 blocks/CU

    ece_main_kernel<<<grid, block, 0, stream>>>(logits, labels, ws, n_rows);
    ece_final_kernel<<<1, 64, 0, stream>>>(ws, out, 1.0f / (float)n_rows);
}

// Round 3
// 66.032 us; speedup vs baseline: 1.9981x; 1.9981x over previous
//
#include <hip/hip_runtime.h>
#include <math.h>

#define ECE_N_BINS 10
#define ECE_C 128

typedef float f32x4 __attribute__((ext_vector_type(4)));

// ws layout (floats): [0..9] counts, [10..19] conf_sum, [20..29] acc_sum

__device__ __forceinline__ void scan8(const f32x4& a, const f32x4& b, int base,
                                      float& v, int& idx)
{
    v = a[0]; idx = base;
    if (a[1] > v) { v = a[1]; idx = base + 1; }
    if (a[2] > v) { v = a[2]; idx = base + 2; }
    if (a[3] > v) { v = a[3]; idx = base + 3; }
    if (b[0] > v) { v = b[0]; idx = base + 4; }
    if (b[1] > v) { v = b[1]; idx = base + 5; }
    if (b[2] > v) { v = b[2]; idx = base + 6; }
    if (b[3] > v) { v = b[3]; idx = base + 7; }
}

__global__ __launch_bounds__(256) void ece_main_kernel(
    const float* __restrict__ logits,
    const int*   __restrict__ labels,
    float*       __restrict__ ws,
    int n_rows)
{
    __shared__ float s_bins[3 * ECE_N_BINS];
    const int tid = threadIdx.x;
    if (tid < 3 * ECE_N_BINS) s_bins[tid] = 0.0f;
    __syncthreads();

    const int lane = tid & 15;     // 16 lanes per row
    const int grp  = tid >> 4;     // 16 groups; each handles 2 rows/iter
    const long long stride = (long long)gridDim.x * 32;   // rows per grid step

    const f32x4* base4 = (const f32x4*)logits;   // 8 float4 per row

    long long row = (long long)blockIdx.x * 32 + grp * 2;
    if (row >= n_rows) {
        __syncthreads();
        if (tid < 3 * ECE_N_BINS) {
            float val = s_bins[tid];
            if (val != 0.0f) atomicAdd(&ws[tid], val);
        }
        return;
    }

    // current pair of rows: each lane holds 2 float4 per row (32 B)
    long long ci = row * 8 + lane * 2;
    f32x4 c0a = base4[ci];     f32x4 c0b = base4[ci + 1];
    f32x4 c1a = base4[ci + 8]; f32x4 c1b = base4[ci + 9];

    while (true) {
        const long long nrow = row + stride;
        const bool has_next = (nrow + 1) < n_rows;   // n_rows%32==0 in practice
        f32x4 n0a, n0b, n1a, n1b;
        if (has_next) {
            long long ni = nrow * 8 + lane * 2;
            n0a = base4[ni];     n0b = base4[ni + 1];
            n1a = base4[ni + 8]; n1b = base4[ni + 9];
        }
        const int lab0 = labels[row];
        const int lab1 = labels[row + 1];

        // in-lane scans (independent -> ILP)
        float v0, v1; int i0, i1;
        const int eb = lane * 8;
        scan8(c0a, c0b, eb, v0, i0);
        scan8(c1a, c1b, eb, v1, i1);

        // interleaved butterflies across the 16-lane group (two independent chains)
        #pragma unroll
        for (int m = 1; m < 16; m <<= 1) {
            float ov0 = __shfl_xor(v0, m, 16);
            int   oi0 = __shfl_xor(i0, m, 16);
            float ov1 = __shfl_xor(v1, m, 16);
            int   oi1 = __shfl_xor(i1, m, 16);
            if (ov0 > v0 || (ov0 == v0 && oi0 < i0)) { v0 = ov0; i0 = oi0; }
            if (ov1 > v1 || (ov1 == v1 && oi1 < i1)) { v1 = ov1; i1 = oi1; }
        }

        if (lane == 0) {
            if (v0 > 0.0f) {
                int bin = (int)ceilf(v0 * (float)ECE_N_BINS) - 1;
                bin = max(0, min(ECE_N_BINS - 1, bin));
                atomicAdd(&s_bins[bin], 1.0f);
                atomicAdd(&s_bins[ECE_N_BINS + bin], v0);
                atomicAdd(&s_bins[2 * ECE_N_BINS + bin], (i0 == lab0) ? 1.0f : 0.0f);
            }
            if (v1 > 0.0f) {
                int bin = (int)ceilf(v1 * (float)ECE_N_BINS) - 1;
                bin = max(0, min(ECE_N_BINS - 1, bin));
                atomicAdd(&s_bins[bin], 1.0f);
                atomicAdd(&s_bins[ECE_N_BINS + bin], v1);
                atomicAdd(&s_bins[2 * ECE_N_BINS + bin], (i1 == lab1) ? 1.0f : 0.0f);
            }
        }

        if (!has_next) break;
        c0a = n0a; c0b = n0b; c1a = n1a; c1b = n1b;
        row = nrow;
    }

    __syncthreads();
    if (tid < 3 * ECE_N_BINS) {
        float val = s_bins[tid];
        if (val != 0.0f) atomicAdd(&ws[tid], val);
    }
}

__global__ void ece_final_kernel(const float* __restrict__ ws,
                                 float* __restrict__ out,
                                 float inv_n)
{
    if (threadIdx.x == 0) {
        float ece = 0.0f;
        #pragma unroll
        for (int b = 0; b < ECE_N_BINS; ++b) {
            float cnt = ws[b];
            if (cnt > 0.0f) {
                float avg_conf = ws[ECE_N_BINS + b]     / cnt;
                float avg_acc  = ws[2 * ECE_N_BINS + b] / cnt;
                ece += fabsf(avg_conf - avg_acc) * cnt * inv_n;
            }
        }
        out[0] = ece;
    }
}

extern "C" void kernel_launch(void* const* d_in, const int* in_sizes, int n_in,
                              void* d_out, int out_size, void* d_ws, size_t ws_size,
                              hipStream_t stream)
{
    const float* logits = (const float*)d_in[0];
    const int*   labels = (const int*)d_in[1];
    float* out = (float*)d_out;
    float* ws  = (float*)d_ws;

    const int n_rows = in_sizes[1];            // labels count = N

    hipMemsetAsync(ws, 0, 3 * ECE_N_BINS * sizeof(float), stream);

    const int block = 256;
    const int rows_per_block = 32;             // 16 groups x 2 rows
    int grid = (n_rows + rows_per_block - 1) / rows_per_block;
    if (grid > 2048) grid = 2048;              // 8 blocks/CU co-resident

    ece_main_kernel<<<grid, block, 0, stream>>>(logits, labels, ws, n_rows);
    ece_final_kernel<<<1, 64, 0, stream>>>(ws, out, 1.0f / (float)n_rows);
}